// Round 6
// baseline (2497.224 us; speedup 1.0000x reference)
//
#include <hip/hip_runtime.h>

// Neural min-sum LDPC decoder, MI355X (gfx950).
// N=131072 vars, M=65536 checks, DV=6, DC=12, T=30 iters.
// Edge (j,l) -> check (A*(j%M)+l) mod 2^16, A=48271 (odd => invertible).
// v2c stored leg-major V[l*NV + jl + half*MC]; gathers coalesced via the
// affine inverse map (consecutive jl -> consecutive addresses).
//
// R5 result: fence-free agent-scope (sc0/sc1) exchange works; kernel is pure
// latency-bound at 1 wave/SIMD. R6: 4 threads per variable-pair
// (2 variables x 2 leg-groups of 3) -> 1024 blocks, 4 waves/SIMD, ~55 loads
// per thread. The reference's SEQUENTIAL 6-term sum is preserved exactly via
// two lane shuffles between the (grp0,grp1) lane pair:
//   grp0: s012=(c0+c1)+c2  --shfl-->  grp1: p=llr+(((s012+c3)+c4)+c5)
//   grp1: p                --shfl-->  grp0 (for its v2c stores p - c_l)
// so the trajectory stays bit-exact vs the numpy reference.
//
// CRITICAL: hipcc defaults to -ffp-contract=fast; FMA contraction perturbs
// the trajectory at 1 ulp and min-sum sign-chaos amplifies it to O(100).
#pragma clang fp contract(off)

#define NV 131072
#define MC 65536
#define DVd 6
#define TT 30
#define EE (NV * DVd)
#define GRIDN 1024u

constexpr unsigned mulinv16(unsigned a) {
  unsigned x = 1;
  for (int i = 0; i < 5; ++i) x *= (2u - a * x); // Newton, mod 2^32
  return x & 0xFFFFu;
}
constexpr unsigned AINV = mulinv16(48271u);
static_assert(((AINV * 48271u) & 0xFFFFu) == 1u, "bad inverse");

static __device__ __forceinline__ float ldv(const float* p) {
  return __hip_atomic_load(p, __ATOMIC_RELAXED, __HIP_MEMORY_SCOPE_AGENT);
}
static __device__ __forceinline__ void stv(float* p, float v) {
  __hip_atomic_store(p, v, __ATOMIC_RELAXED, __HIP_MEMORY_SCOPE_AGENT);
}
static __device__ __forceinline__ unsigned ldb(const unsigned char* p) {
  return (unsigned)__hip_atomic_load(p, __ATOMIC_RELAXED,
                                     __HIP_MEMORY_SCOPE_AGENT);
}
static __device__ __forceinline__ void stb(unsigned char* p, unsigned char v) {
  __hip_atomic_store(p, v, __ATOMIC_RELAXED, __HIP_MEMORY_SCOPE_AGENT);
}

static __device__ __forceinline__ void upd2(float a, float& m1, float& m2) {
  if (a < m1) { m2 = m1; m1 = a; }
  else if (a < m2) { m2 = a; }
}

extern "C" __global__ void __launch_bounds__(256, 4)
ldpc_kernel(const float* __restrict__ llr,
            const float* __restrict__ betas,
            float* __restrict__ out,
            float* __restrict__ v2cA,
            float* __restrict__ v2cB,
            unsigned char* __restrict__ bitsA,
            unsigned char* __restrict__ bitsB,
            unsigned* __restrict__ bar)
{
  const unsigned tid = threadIdx.x;
  const unsigned t   = blockIdx.x * blockDim.x + tid;  // 0..262143
  const unsigned var = t >> 1;                         // 0..131071
  const unsigned grp = t & 1;                          // leg-group: 0->l 0..2, 1->l 3..5
  const unsigned jl  = var & 0xFFFFu;                  // check-row seed
  const unsigned h   = var >> 16;                      // half (0 lower, 1 upper)
  const unsigned dlo = 3u * grp;
  const float llr_v  = llr[var];

  // window indices: d = dlo..dlo+7 covers all (l,lp) combos for legs l=dlo..dlo+2
  unsigned idx8[8];
#pragma unroll
  for (int k = 0; k < 8; ++k)
    idx8[k] = (jl + AINV * (unsigned)((int)dlo + k - 5)) & 0xFFFFu;

  __shared__ int s_unsat;
  __shared__ int s_ok; // ok at iter (it-2), published by tid0 at each barrier

  float pA = 0.f; // posterior from iter it-1
  float pB = 0.f; // posterior from iter it-2

  // betas prefetch registers for this thread's 3 legs of the upcoming iter
  float nb[3];
  {
    const float* b = betas + (size_t)var * DVd + dlo;
    nb[0] = b[0]; nb[1] = b[1]; nb[2] = b[2];
  }

  for (int it = 0; it < TT; ++it) {
    // ---- early-exit: ok at iter it-2 (payload of bar[it-1]'s spin) ----
    if (it >= 2 && s_ok) { // state froze at it-2
      if (grp) {
        out[var]      = (pB < 0.0f) ? 1.0f : 0.0f;
        out[NV + var] = pB;
        if (var == 0) out[2 * NV] = (float)(it - 1); // iters
      }
      return; // uniform across the grid
    }
    if (tid == 0) s_unsat = 0;
    __syncthreads(); // S1

    float* vout = (it & 1) ? v2cB : v2cA;
    const unsigned char* Bprev = (it & 1) ? bitsA : bitsB;
    unsigned char* Bcur = (it & 1) ? bitsB : bitsA;

    // ---- batched load window: 36 v2c gathers (or 16 llr) + 16 syndrome bytes ----
    float A0[DVd][3], A1[DVd][3]; // [lp][li]: member (lp, both halves) of check dlo+li
    if (it == 0) {
      float w0[8], w1[8];
#pragma unroll
      for (int k = 0; k < 8; ++k) {
        w0[k] = llr[idx8[k]];
        w1[k] = llr[idx8[k] + MC];
      }
#pragma unroll
      for (int lp = 0; lp < DVd; ++lp)
#pragma unroll
        for (int li = 0; li < 3; ++li) {
          A0[lp][li] = w0[li - lp + 5];
          A1[lp][li] = w1[li - lp + 5];
        }
    } else {
      const float* vin = (it & 1) ? v2cA : v2cB;
#pragma unroll
      for (int lp = 0; lp < DVd; ++lp) {
        const float* p = vin + (size_t)lp * NV;
#pragma unroll
        for (int li = 0; li < 3; ++li) {
          const unsigned r = idx8[li - lp + 5];
          A0[lp][li] = ldv(p + r);
          A1[lp][li] = ldv(p + r + MC);
        }
      }
    }
    unsigned ubl[8], ubu[8];
    if (it >= 1) {
#pragma unroll
      for (int k = 0; k < 8; ++k) {
        ubl[k] = ldb(Bprev + idx8[k]);
        ubu[k] = ldb(Bprev + idx8[k] + MC);
      }
    }

    // ---- check-node update for this thread's 3 legs ----
    float c[3];
#pragma unroll
    for (int li = 0; li < 3; ++li) {
      float m1 = 1e30f, m2 = 1e30f;
      int par = 0;
#pragma unroll
      for (int lp = 0; lp < DVd; ++lp) {
        const float a = A0[lp][li];
        const float b = A1[lp][li];
        par ^= (a < 0.0f) ? 1 : 0;
        par ^= (b < 0.0f) ? 1 : 0;
        upd2(fabsf(a), m1, m2);
        upd2(fabsf(b), m1, m2);
      }
      // own edge: plane lp == l == dlo+li  ->  window k = li - l + 5 = 5 - dlo
      const float own = h ? A1[dlo + li][li] : A0[dlo + li][li];
      const int n = (own < 0.0f) ? 1 : 0;
      const float v = (fabsf(own) == m1) ? m2 : m1;
      const float u = ((par ^ n) != 0) ? -v : v;
      c[li] = nb[li] * u; // beta * c2v-magnitude (one rounded mul)
    }

    // ---- syndrome of iteration it-1 ----
    if (it >= 1) {
      unsigned myunsat = 0;
#pragma unroll
      for (int li = 0; li < 3; ++li) {
        unsigned P = 0;
#pragma unroll
        for (int lp = 0; lp < DVd; ++lp)
          P ^= ubl[li - lp + 5] ^ ubu[li - lp + 5];
        myunsat |= P;
      }
      if (myunsat) s_unsat = 1; // benign same-value race
    }

    // ---- variable-node update: exact sequential 6-term sum via shuffles ----
    const float s3 = (c[0] + c[1]) + c[2];    // grp0: c0+c1+c2 ; grp1: unused combo
    const float s3o = __shfl_xor(s3, 1);      // grp1 receives grp0's s012
    float P = 0.0f;
    if (grp) P = llr_v + (((s3o + c[0]) + c[1]) + c[2]); // ((s012+c3)+c4)+c5
    const float Po = __shfl_xor(P, 1);        // grp0 receives true posterior
    if (!grp) P = Po;

    if (it < TT - 1) {
#pragma unroll
      for (int li = 0; li < 3; ++li)
        stv(vout + (size_t)(dlo + li) * NV + jl + h * MC, P - c[li]);
      if (grp) stb(Bcur + var, (unsigned char)((P < 0.0f) ? 1 : 0));
    }

    // ---- prefetch next iteration's betas (overlaps barrier wait) ----
    if (it + 1 < TT) {
      const float* b = betas + (size_t)(it + 1) * EE + (size_t)var * DVd + dlo;
      nb[0] = b[0]; nb[1] = b[1]; nb[2] = b[2];
    }

    // ---- grid barrier: per-iteration payload counter, no fences ----
    __syncthreads(); // S2: drains sc1 stores (vmcnt 0) before arrival-add
    if (tid == 0) {
      const unsigned add = 1u | (s_unsat ? 0x10000u : 0u);
      __hip_atomic_fetch_add(&bar[it], add, __ATOMIC_RELAXED,
                             __HIP_MEMORY_SCOPE_AGENT);
      unsigned v;
      for (;;) {
        v = __hip_atomic_load(&bar[it], __ATOMIC_RELAXED,
                              __HIP_MEMORY_SCOPE_AGENT);
        if ((v & 0xFFFFu) == GRIDN) break;
        __builtin_amdgcn_s_sleep(2);
      }
      s_ok = ((v >> 16) == 0u); // all checks satisfied at iter it-1
    }
    __syncthreads(); // S3

    pB = pA;
    pA = P;
  }

  // ---- tail: s_ok now = ok at iter 28 (payload of bar[29]) ----
  if (grp) {
    float q, itrs;
    if (s_ok) { q = pB; itrs = (float)(TT - 1); } // froze at 28
    else      { q = pA; itrs = (float)TT; }       // ran all 30
    out[var]      = (q < 0.0f) ? 1.0f : 0.0f;
    out[NV + var] = q;
    if (var == 0) out[2 * NV] = itrs;
  }
}

extern "C" void kernel_launch(void* const* d_in, const int* in_sizes, int n_in,
                              void* d_out, int out_size, void* d_ws, size_t ws_size,
                              hipStream_t stream) {
  const float* llr   = (const float*)d_in[0];
  const float* betas = (const float*)d_in[1];
  // d_in[2]=check_idx, d_in[3]=var_idx, d_in[4]=num_checks: affine-known.
  float* out = (float*)d_out;

  char* ws = (char*)d_ws;
  unsigned* bar = (unsigned*)ws;                        // 32 per-iter counters
  float* v2cA = (float*)(ws + 4096);
  float* v2cB = (float*)(ws + 4096 + (size_t)EE * 4);
  unsigned char* bitsA = (unsigned char*)(ws + 4096 + 2 * (size_t)EE * 4);
  unsigned char* bitsB = bitsA + (size_t)NV; // one byte per variable

  hipMemsetAsync(ws, 0, 256, stream); // zero the per-iteration counters

  dim3 grid(GRIDN), block(256);
  hipLaunchKernelGGL(ldpc_kernel, grid, block, 0, stream,
                     llr, betas, out, v2cA, v2cB, bitsA, bitsB, bar);
}

// Round 8
// 1157.068 us; speedup vs baseline: 2.1582x; 2.1582x over previous
//
#include <hip/hip_runtime.h>

// Neural min-sum LDPC decoder, MI355X (gfx950).
// N=131072 vars, M=65536 checks, DV=6, DC=12, T=30 iters.
// Edge (j,l) -> check (A*(j%M)+l) mod 2^16, A=48271 (odd => invertible).
// v2c stored leg-major V[l*NV + jl (+MC)]; gathers coalesced via the affine
// inverse map. One thread per variable PAIR (jl, jl+M) — shares all 6 checks.
//
// R8 (= R7 with compile fix): R5's __hip_atomic_load gathers were SERIALIZED
// (atomics never cluster): 72 x ~650cy MALL round trips = the 34 us/iter.
// Raw buffer load/store intrinsics with cache policy sc0|sc1 (aux=17) keep
// the same MALL-direct coherence semantics as agent-scope relaxed atomics
// (no stale per-XCD L2 lines) but are plain loads to the scheduler -> all
// ~94 gathers issue in one clustered window (~2 round trips). Syndrome hard
// bits come from a double-buffered posterior plane (float sign), loaded in
// the same window.
//
// CRITICAL: hipcc defaults to -ffp-contract=fast; FMA contraction perturbs
// the trajectory at 1 ulp and min-sum sign-chaos amplifies it to O(100).
#pragma clang fp contract(off)

#define NV 131072
#define MC 65536
#define DVd 6
#define TT 30
#define EE (NV * DVd)
#define GRIDN 256u
#define SC01 17  // CPol: SC0(=1) | SC1(=16) -> L1+L2 bypass, MALL coherent

constexpr unsigned mulinv16(unsigned a) {
  unsigned x = 1;
  for (int i = 0; i < 5; ++i) x *= (2u - a * x); // Newton, mod 2^32
  return x & 0xFFFFu;
}
constexpr unsigned AINV = mulinv16(48271u);
static_assert(((AINV * 48271u) & 0xFFFFu) == 1u, "bad inverse");

// ---- raw buffer access with explicit cache policy (ROCm 7 signatures) ----
using rsrc_t = __amdgpu_buffer_rsrc_t;
static __device__ __forceinline__ rsrc_t mkrsrc(void* p) {
  // stride=0, num_records=-1 (bounds check off), flags=raw dword SRD
  return __builtin_amdgcn_make_buffer_rsrc(p, (short)0, -1, 0x00020000);
}
static __device__ __forceinline__ float bload(rsrc_t r, int off) {
  int v = __builtin_amdgcn_raw_buffer_load_b32(r, off, 0, SC01);
  return __builtin_bit_cast(float, v);
}
static __device__ __forceinline__ void bstore(rsrc_t r, int off, float x) {
  __builtin_amdgcn_raw_buffer_store_b32(__builtin_bit_cast(int, x),
                                        r, off, 0, SC01);
}

static __device__ __forceinline__ void upd2(float a, float& m1, float& m2) {
  if (a < m1) { m2 = m1; m1 = a; }
  else if (a < m2) { m2 = a; }
}

extern "C" __global__ void __launch_bounds__(256, 1)
ldpc_kernel(const float* __restrict__ llr,
            const float* __restrict__ betas,
            float* __restrict__ out,
            float* __restrict__ v2cA,
            float* __restrict__ v2cB,
            float* __restrict__ postA,
            float* __restrict__ postB,
            unsigned* __restrict__ bar)
{
  const unsigned tid = threadIdx.x;
  const unsigned jl = blockIdx.x * blockDim.x + tid; // 0..65535
  const float llr0 = llr[jl];
  const float llr1 = llr[jl + MC];

  const rsrc_t rA  = mkrsrc(v2cA);
  const rsrc_t rB  = mkrsrc(v2cB);
  const rsrc_t rPA = mkrsrc(postA);
  const rsrc_t rPB = mkrsrc(postB);

  // rotated variable indices per delta = l - l' in [-5,5]
  unsigned idx[11];
#pragma unroll
  for (int d = 0; d < 11; ++d)
    idx[d] = (jl + AINV * (unsigned)(d - 5)) & 0xFFFFu;

  __shared__ int s_unsat;
  __shared__ int s_ok; // ok at iter (it-2), published by tid0 at each barrier

  float pA0 = 0.f, pA1 = 0.f; // posterior from iter it-1
  float pB0 = 0.f, pB1 = 0.f; // posterior from iter it-2

  // betas prefetch registers (for the upcoming iteration)
  float2 nb0[3], nb1[3];
  {
    const float2* b0 = (const float2*)(betas + (size_t)jl * DVd);
    const float2* b1 = (const float2*)(betas + (size_t)(jl + MC) * DVd);
    nb0[0] = b0[0]; nb0[1] = b0[1]; nb0[2] = b0[2];
    nb1[0] = b1[0]; nb1[1] = b1[1]; nb1[2] = b1[2];
  }

  for (int it = 0; it < TT; ++it) {
    // ---- early-exit: ok at iter it-2 (payload of bar[it-1]'s spin) ----
    if (it >= 2 && s_ok) { // state froze at it-2
      out[jl]           = (pB0 < 0.0f) ? 1.0f : 0.0f;
      out[jl + MC]      = (pB1 < 0.0f) ? 1.0f : 0.0f;
      out[NV + jl]      = pB0;
      out[NV + jl + MC] = pB1;
      if (jl == 0) out[2 * NV] = (float)(it - 1); // iters
      return; // uniform across the grid
    }
    if (tid == 0) s_unsat = 0;
    __syncthreads(); // S1

    const rsrc_t vin  = (it & 1) ? rA : rB;
    const rsrc_t vout = (it & 1) ? rB : rA;
    const rsrc_t pin  = (it & 1) ? rPA : rPB;
    const rsrc_t pout = (it & 1) ? rPB : rPA;

    // ---- clustered load window: 72 v2c + 22 posterior floats ----
    float A0[DVd][DVd], A1[DVd][DVd]; // [lp][l] = plane lp at idx[l-lp+5]
    float q0[11], q1[11];             // prev posterior (syndrome signs)
    if (it == 0) {
      float w0[11], w1[11];
#pragma unroll
      for (int d = 0; d < 11; ++d) {
        w0[d] = llr[idx[d]];
        w1[d] = llr[idx[d] + MC];
      }
#pragma unroll
      for (int lp = 0; lp < DVd; ++lp)
#pragma unroll
        for (int l = 0; l < DVd; ++l) {
          A0[lp][l] = w0[l - lp + 5];
          A1[lp][l] = w1[l - lp + 5];
        }
    } else {
#pragma unroll
      for (int lp = 0; lp < DVd; ++lp) {
#pragma unroll
        for (int l = 0; l < DVd; ++l) {
          const int off = (int)((lp * NV + idx[l - lp + 5]) * 4u);
          A0[lp][l] = bload(vin, off);
          A1[lp][l] = bload(vin, off + MC * 4);
        }
      }
#pragma unroll
      for (int d = 0; d < 11; ++d) {
        q0[d] = bload(pin, (int)(idx[d] * 4u));
        q1[d] = bload(pin, (int)((idx[d] + MC) * 4u));
      }
    }

    // ---- check-node update (same op order as reference) ----
    float u0[DVd], u1[DVd];
#pragma unroll
    for (int l = 0; l < DVd; ++l) {
      float m1 = 1e30f, m2 = 1e30f;
      int par = 0;
#pragma unroll
      for (int lp = 0; lp < DVd; ++lp) {
        const float a = A0[lp][l];
        const float b = A1[lp][l];
        par ^= (a < 0.0f) ? 1 : 0;
        par ^= (b < 0.0f) ? 1 : 0;
        upd2(fabsf(a), m1, m2);
        upd2(fabsf(b), m1, m2);
      }
      const float own0 = A0[l][l];
      const float own1 = A1[l][l];
      const int n0 = (own0 < 0.0f) ? 1 : 0;
      const float v = (fabsf(own0) == m1) ? m2 : m1;
      u0[l] = ((par ^ n0) != 0) ? -v : v;
      const int n1 = (own1 < 0.0f) ? 1 : 0;
      const float w = (fabsf(own1) == m1) ? m2 : m1;
      u1[l] = ((par ^ n1) != 0) ? -w : w;
    }

    // ---- syndrome of iteration it-1 (signs of prev posterior) ----
    if (it >= 1) {
      unsigned sb[11];
#pragma unroll
      for (int d = 0; d < 11; ++d)
        sb[d] = ((q0[d] < 0.0f) ? 1u : 0u) ^ ((q1[d] < 0.0f) ? 1u : 0u);
      unsigned myunsat = 0;
#pragma unroll
      for (int l = 0; l < DVd; ++l)
        myunsat |= sb[l] ^ sb[l+1] ^ sb[l+2] ^ sb[l+3] ^ sb[l+4] ^ sb[l+5];
      if (myunsat) s_unsat = 1; // benign same-value race
    }

    // ---- variable-node update (betas from prefetch registers) ----
    const float b0v[DVd] = { nb0[0].x, nb0[0].y, nb0[1].x,
                             nb0[1].y, nb0[2].x, nb0[2].y };
    const float b1v[DVd] = { nb1[0].x, nb1[0].y, nb1[1].x,
                             nb1[1].y, nb1[2].x, nb1[2].y };
    float c0[DVd], c1[DVd];
    float vs0 = 0.0f, vs1 = 0.0f;
#pragma unroll
    for (int l = 0; l < DVd; ++l) {
      c0[l] = b0v[l] * u0[l];
      vs0 += c0[l];
    }
#pragma unroll
    for (int l = 0; l < DVd; ++l) {
      c1[l] = b1v[l] * u1[l];
      vs1 += c1[l];
    }
    const float p0 = llr0 + vs0;
    const float p1 = llr1 + vs1;

    if (it < TT - 1) {
#pragma unroll
      for (int l = 0; l < DVd; ++l) {
        const int off = (int)((l * NV + jl) * 4u);
        bstore(vout, off,          p0 - c0[l]);
        bstore(vout, off + MC * 4, p1 - c1[l]);
      }
      bstore(pout, (int)(jl * 4u),        p0);
      bstore(pout, (int)((jl + MC) * 4u), p1);
    }

    // ---- prefetch next iteration's betas (overlaps barrier wait) ----
    if (it + 1 < TT) {
      const float* bt = betas + (size_t)(it + 1) * EE;
      const float2* b0 = (const float2*)(bt + (size_t)jl * DVd);
      const float2* b1 = (const float2*)(bt + (size_t)(jl + MC) * DVd);
      nb0[0] = b0[0]; nb0[1] = b0[1]; nb0[2] = b0[2];
      nb1[0] = b1[0]; nb1[1] = b1[1]; nb1[2] = b1[2];
    }

    // ---- grid barrier: per-iteration payload counter, no fences ----
    // __syncthreads drains each wave's buffer stores (vmcnt 0) => globally
    // visible (write-through sc0|sc1) before any block's arrival-add.
    __syncthreads(); // S2
    if (tid == 0) {
      const unsigned add = 1u | (s_unsat ? 0x10000u : 0u);
      __hip_atomic_fetch_add(&bar[it], add, __ATOMIC_RELAXED,
                             __HIP_MEMORY_SCOPE_AGENT);
      unsigned v;
      for (;;) {
        v = __hip_atomic_load(&bar[it], __ATOMIC_RELAXED,
                              __HIP_MEMORY_SCOPE_AGENT);
        if ((v & 0xFFFFu) == GRIDN) break;
        __builtin_amdgcn_s_sleep(2);
      }
      s_ok = ((v >> 16) == 0u); // all checks satisfied at iter it-1
    }
    __syncthreads(); // S3

    pB0 = pA0; pB1 = pA1;
    pA0 = p0;  pA1 = p1;
  }

  // ---- tail: s_ok now = ok at iter 28 (payload of bar[29]) ----
  {
    float q0t, q1t, itrs;
    if (s_ok) { q0t = pB0; q1t = pB1; itrs = (float)(TT - 1); } // froze at 28
    else      { q0t = pA0; q1t = pA1; itrs = (float)TT; }       // ran all 30
    out[jl]           = (q0t < 0.0f) ? 1.0f : 0.0f;
    out[jl + MC]      = (q1t < 0.0f) ? 1.0f : 0.0f;
    out[NV + jl]      = q0t;
    out[NV + jl + MC] = q1t;
    if (jl == 0) out[2 * NV] = itrs;
  }
}

extern "C" void kernel_launch(void* const* d_in, const int* in_sizes, int n_in,
                              void* d_out, int out_size, void* d_ws, size_t ws_size,
                              hipStream_t stream) {
  const float* llr   = (const float*)d_in[0];
  const float* betas = (const float*)d_in[1];
  // d_in[2]=check_idx, d_in[3]=var_idx, d_in[4]=num_checks: affine-known.
  float* out = (float*)d_out;

  char* ws = (char*)d_ws;
  unsigned* bar = (unsigned*)ws;                        // 32 per-iter counters
  float* v2cA  = (float*)(ws + 4096);
  float* v2cB  = v2cA + (size_t)EE;
  float* postA = v2cB + (size_t)EE;
  float* postB = postA + (size_t)NV;

  (void)hipMemsetAsync(ws, 0, 256, stream); // zero per-iteration counters

  dim3 grid(GRIDN), block(256);
  hipLaunchKernelGGL(ldpc_kernel, grid, block, 0, stream,
                     llr, betas, out, v2cA, v2cB, postA, postB, bar);
}

// Round 10
// 828.893 us; speedup vs baseline: 3.0127x; 1.3959x over previous
//
#include <hip/hip_runtime.h>

// Neural min-sum LDPC decoder, MI355X (gfx950).
// N=131072 vars, M=65536 checks, DV=6, DC=12, T=30 iters.
// Edge (j,l) -> check (A*(j%M)+l) mod 2^16, A=48271 (odd => invertible).
// v2c stored leg-major V[l*NV + jl (+MC)]; gathers coalesced via the affine
// inverse map. One thread per variable PAIR (jl, jl+M) — shares all 6 checks.
// All cross-XCD data uses raw buffer ops with CPol sc0|sc1 (MALL-coherent,
// L1/L2-bypass); syndrome bits come from a double-buffered posterior plane.
//
// R10 (= R9 barrier, hang fixed): R9 polled the barrier with raw buffer
// loads — readonly intrinsics with invariant args, so LICM hoisted them out
// of the spin loops => infinite spin. ALL polling loads are now
// __hip_atomic_load (relaxed/agent: re-issued every trip). Data-path loads
// stay raw sc0|sc1 (consumed once per iteration, hoisting impossible).
// Barrier: arrivals spread over 16 per-iteration 64B-strided group counters
// (<=16 atomics/line); block 0 sweeps them, then broadcasts release over 16
// per-iteration flag lines; each block polls only its group's flag.
//
// CRITICAL: hipcc defaults to -ffp-contract=fast; FMA contraction perturbs
// the trajectory at 1 ulp and min-sum sign-chaos amplifies it to O(100).
#pragma clang fp contract(off)

#define NV 131072
#define MC 65536
#define DVd 6
#define TT 30
#define EE (NV * DVd)
#define GRIDN 256u
#define NGRP 16u
#define SC01 17  // CPol: SC0(=1) | SC1(=16) -> L1+L2 bypass, MALL coherent

constexpr unsigned mulinv16(unsigned a) {
  unsigned x = 1;
  for (int i = 0; i < 5; ++i) x *= (2u - a * x); // Newton, mod 2^32
  return x & 0xFFFFu;
}
constexpr unsigned AINV = mulinv16(48271u);
static_assert(((AINV * 48271u) & 0xFFFFu) == 1u, "bad inverse");

// ---- raw buffer access with explicit cache policy (ROCm 7 signatures) ----
using rsrc_t = __amdgpu_buffer_rsrc_t;
static __device__ __forceinline__ rsrc_t mkrsrc(void* p) {
  return __builtin_amdgcn_make_buffer_rsrc(p, (short)0, -1, 0x00020000);
}
static __device__ __forceinline__ float bload(rsrc_t r, int off) {
  int v = __builtin_amdgcn_raw_buffer_load_b32(r, off, 0, SC01);
  return __builtin_bit_cast(float, v);
}
static __device__ __forceinline__ void bstore(rsrc_t r, int off, float x) {
  __builtin_amdgcn_raw_buffer_store_b32(__builtin_bit_cast(int, x),
                                        r, off, 0, SC01);
}
static __device__ __forceinline__ void bustore(rsrc_t r, int off, unsigned x) {
  __builtin_amdgcn_raw_buffer_store_b32((int)x, r, off, 0, SC01);
}
static __device__ __forceinline__ unsigned aload(const unsigned* p) {
  return __hip_atomic_load(p, __ATOMIC_RELAXED, __HIP_MEMORY_SCOPE_AGENT);
}

static __device__ __forceinline__ void upd2(float a, float& m1, float& m2) {
  if (a < m1) { m2 = m1; m1 = a; }
  else if (a < m2) { m2 = a; }
}

extern "C" __global__ void __launch_bounds__(256, 1)
ldpc_kernel(const float* __restrict__ llr,
            const float* __restrict__ betas,
            float* __restrict__ out,
            float* __restrict__ v2cA,
            float* __restrict__ v2cB,
            float* __restrict__ postA,
            float* __restrict__ postB,
            unsigned* __restrict__ arr,   // [TT*16] counters, 64B-strided
            unsigned* __restrict__ rel)   // [TT*16] flags, 64B-strided
{
  const unsigned tid = threadIdx.x;
  const unsigned jl = blockIdx.x * blockDim.x + tid; // 0..65535
  const float llr0 = llr[jl];
  const float llr1 = llr[jl + MC];

  const rsrc_t rA   = mkrsrc(v2cA);
  const rsrc_t rB   = mkrsrc(v2cB);
  const rsrc_t rPA  = mkrsrc(postA);
  const rsrc_t rPB  = mkrsrc(postB);
  const rsrc_t rREL = mkrsrc(rel);

  // rotated variable indices per delta = l - l' in [-5,5]
  unsigned idx[11];
#pragma unroll
  for (int d = 0; d < 11; ++d)
    idx[d] = (jl + AINV * (unsigned)(d - 5)) & 0xFFFFu;

  __shared__ int s_unsat;
  __shared__ int s_ok; // ok at iter (it-1), published by tid0 at each barrier

  float pA0 = 0.f, pA1 = 0.f; // posterior from iter it-1
  float pB0 = 0.f, pB1 = 0.f; // posterior from iter it-2

  // betas prefetch registers (for the upcoming iteration)
  float2 nb0[3], nb1[3];
  {
    const float2* b0 = (const float2*)(betas + (size_t)jl * DVd);
    const float2* b1 = (const float2*)(betas + (size_t)(jl + MC) * DVd);
    nb0[0] = b0[0]; nb0[1] = b0[1]; nb0[2] = b0[2];
    nb1[0] = b1[0]; nb1[1] = b1[1]; nb1[2] = b1[2];
  }

  for (int it = 0; it < TT; ++it) {
    // ---- early-exit: ok at iter it-2 (set at barrier it-1) ----
    if (it >= 2 && s_ok) { // state froze at it-2
      out[jl]           = (pB0 < 0.0f) ? 1.0f : 0.0f;
      out[jl + MC]      = (pB1 < 0.0f) ? 1.0f : 0.0f;
      out[NV + jl]      = pB0;
      out[NV + jl + MC] = pB1;
      if (jl == 0) out[2 * NV] = (float)(it - 1); // iters
      return; // uniform across the grid
    }
    if (tid == 0) s_unsat = 0;
    __syncthreads(); // S1

    const rsrc_t vin  = (it & 1) ? rA : rB;
    const rsrc_t vout = (it & 1) ? rB : rA;
    const rsrc_t pin  = (it & 1) ? rPA : rPB;
    const rsrc_t pout = (it & 1) ? rPB : rPA;

    // ---- clustered load window: 72 v2c + 22 posterior floats ----
    float A0[DVd][DVd], A1[DVd][DVd]; // [lp][l] = plane lp at idx[l-lp+5]
    float q0[11], q1[11];             // prev posterior (syndrome signs)
    if (it == 0) {
      float w0[11], w1[11];
#pragma unroll
      for (int d = 0; d < 11; ++d) {
        w0[d] = llr[idx[d]];
        w1[d] = llr[idx[d] + MC];
      }
#pragma unroll
      for (int lp = 0; lp < DVd; ++lp)
#pragma unroll
        for (int l = 0; l < DVd; ++l) {
          A0[lp][l] = w0[l - lp + 5];
          A1[lp][l] = w1[l - lp + 5];
        }
    } else {
#pragma unroll
      for (int lp = 0; lp < DVd; ++lp) {
#pragma unroll
        for (int l = 0; l < DVd; ++l) {
          const int off = (int)((lp * NV + idx[l - lp + 5]) * 4u);
          A0[lp][l] = bload(vin, off);
          A1[lp][l] = bload(vin, off + MC * 4);
        }
      }
#pragma unroll
      for (int d = 0; d < 11; ++d) {
        q0[d] = bload(pin, (int)(idx[d] * 4u));
        q1[d] = bload(pin, (int)((idx[d] + MC) * 4u));
      }
    }

    // ---- check-node update (same op order as reference) ----
    float u0[DVd], u1[DVd];
#pragma unroll
    for (int l = 0; l < DVd; ++l) {
      float m1 = 1e30f, m2 = 1e30f;
      int par = 0;
#pragma unroll
      for (int lp = 0; lp < DVd; ++lp) {
        const float a = A0[lp][l];
        const float b = A1[lp][l];
        par ^= (a < 0.0f) ? 1 : 0;
        par ^= (b < 0.0f) ? 1 : 0;
        upd2(fabsf(a), m1, m2);
        upd2(fabsf(b), m1, m2);
      }
      const float own0 = A0[l][l];
      const float own1 = A1[l][l];
      const int n0 = (own0 < 0.0f) ? 1 : 0;
      const float v = (fabsf(own0) == m1) ? m2 : m1;
      u0[l] = ((par ^ n0) != 0) ? -v : v;
      const int n1 = (own1 < 0.0f) ? 1 : 0;
      const float w = (fabsf(own1) == m1) ? m2 : m1;
      u1[l] = ((par ^ n1) != 0) ? -w : w;
    }

    // ---- syndrome of iteration it-1 (signs of prev posterior) ----
    if (it >= 1) {
      unsigned sb[11];
#pragma unroll
      for (int d = 0; d < 11; ++d)
        sb[d] = ((q0[d] < 0.0f) ? 1u : 0u) ^ ((q1[d] < 0.0f) ? 1u : 0u);
      unsigned myunsat = 0;
#pragma unroll
      for (int l = 0; l < DVd; ++l)
        myunsat |= sb[l] ^ sb[l+1] ^ sb[l+2] ^ sb[l+3] ^ sb[l+4] ^ sb[l+5];
      if (myunsat) s_unsat = 1; // benign same-value race
    }

    // ---- variable-node update (betas from prefetch registers) ----
    const float b0v[DVd] = { nb0[0].x, nb0[0].y, nb0[1].x,
                             nb0[1].y, nb0[2].x, nb0[2].y };
    const float b1v[DVd] = { nb1[0].x, nb1[0].y, nb1[1].x,
                             nb1[1].y, nb1[2].x, nb1[2].y };
    float c0[DVd], c1[DVd];
    float vs0 = 0.0f, vs1 = 0.0f;
#pragma unroll
    for (int l = 0; l < DVd; ++l) {
      c0[l] = b0v[l] * u0[l];
      vs0 += c0[l];
    }
#pragma unroll
    for (int l = 0; l < DVd; ++l) {
      c1[l] = b1v[l] * u1[l];
      vs1 += c1[l];
    }
    const float p0 = llr0 + vs0;
    const float p1 = llr1 + vs1;

    if (it < TT - 1) {
#pragma unroll
      for (int l = 0; l < DVd; ++l) {
        const int off = (int)((l * NV + jl) * 4u);
        bstore(vout, off,          p0 - c0[l]);
        bstore(vout, off + MC * 4, p1 - c1[l]);
      }
      bstore(pout, (int)(jl * 4u),        p0);
      bstore(pout, (int)((jl + MC) * 4u), p1);
    }

    // ---- prefetch next iteration's betas (overlaps barrier wait) ----
    if (it + 1 < TT) {
      const float* bt = betas + (size_t)(it + 1) * EE;
      const float2* b0 = (const float2*)(bt + (size_t)jl * DVd);
      const float2* b1 = (const float2*)(bt + (size_t)(jl + MC) * DVd);
      nb0[0] = b0[0]; nb0[1] = b0[1]; nb0[2] = b0[2];
      nb1[0] = b1[0]; nb1[1] = b1[1]; nb1[2] = b1[2];
    }

    // ---- grid barrier: distributed arrival + broadcast release ----
    // __syncthreads drains each wave's buffer stores (vmcnt 0) before the
    // arrival-add; all data reads are MALL-direct, so arrival implies data.
    __syncthreads(); // S2
    if (tid == 0) {
      const unsigned g = blockIdx.x & (NGRP - 1u);
      unsigned* ap = arr + ((unsigned)it * NGRP + g) * 16u; // own 64B line
      __hip_atomic_fetch_add(ap, 1u | (s_unsat ? 0x10000u : 0u),
                             __ATOMIC_RELAXED, __HIP_MEMORY_SCOPE_AGENT);
      const unsigned* abase = arr + (unsigned)it * NGRP * 16u;
      const int relbase = (int)((unsigned)it * NGRP * 64u);
      if (blockIdx.x == 0) {
        // detector: sweep the 16 group counters (atomic loads, never hoisted)
        unsigned lo, hi;
        for (;;) {
          lo = 0; hi = 0;
#pragma unroll
          for (int k = 0; k < (int)NGRP; ++k) {
            const unsigned raw = aload(abase + k * 16);
            lo += raw & 0xFFFFu;
            hi += raw >> 16;
          }
          if (lo == GRIDN) break;
          __builtin_amdgcn_s_sleep(1);
        }
        const unsigned relv = 1u | ((hi == 0u) ? 2u : 0u);
#pragma unroll
        for (int k = 0; k < (int)NGRP; ++k)
          bustore(rREL, relbase + k * 64, relv);
        s_ok = (relv & 2u) != 0;
      } else {
        const unsigned* rp = rel + (unsigned)it * NGRP * 16u + g * 16u;
        unsigned v;
        for (;;) {
          v = aload(rp);
          if (v != 0u) break;
          __builtin_amdgcn_s_sleep(4);
        }
        s_ok = (v & 2u) != 0;
      }
    }
    __syncthreads(); // S3

    pB0 = pA0; pB1 = pA1;
    pA0 = p0;  pA1 = p1;
  }

  // ---- tail: s_ok now = ok at iter 28 (set at barrier 29) ----
  {
    float q0t, q1t, itrs;
    if (s_ok) { q0t = pB0; q1t = pB1; itrs = (float)(TT - 1); } // froze at 28
    else      { q0t = pA0; q1t = pA1; itrs = (float)TT; }       // ran all 30
    out[jl]           = (q0t < 0.0f) ? 1.0f : 0.0f;
    out[jl + MC]      = (q1t < 0.0f) ? 1.0f : 0.0f;
    out[NV + jl]      = q0t;
    out[NV + jl + MC] = q1t;
    if (jl == 0) out[2 * NV] = itrs;
  }
}

extern "C" void kernel_launch(void* const* d_in, const int* in_sizes, int n_in,
                              void* d_out, int out_size, void* d_ws, size_t ws_size,
                              hipStream_t stream) {
  const float* llr   = (const float*)d_in[0];
  const float* betas = (const float*)d_in[1];
  // d_in[2]=check_idx, d_in[3]=var_idx, d_in[4]=num_checks: affine-known.
  float* out = (float*)d_out;

  char* ws = (char*)d_ws;
  unsigned* arr = (unsigned*)ws;                    // TT*16 counters, 64B-strided
  unsigned* rel = (unsigned*)(ws + 32768);          // TT*16 flags, 64B-strided
  float* v2cA  = (float*)(ws + 65536);
  float* v2cB  = v2cA + (size_t)EE;
  float* postA = v2cB + (size_t)EE;
  float* postB = postA + (size_t)NV;

  (void)hipMemsetAsync(ws, 0, 65536, stream); // zero arrival + release lines

  dim3 grid(GRIDN), block(256);
  hipLaunchKernelGGL(ldpc_kernel, grid, block, 0, stream,
                     llr, betas, out, v2cA, v2cB, postA, postB, arr, rel);
}